// Round 11
// baseline (147.010 us; speedup 1.0000x reference)
//
#include <hip/hip_runtime.h>

#define BB 64
#define C1 3
#define LIN 8192
#define PAD1 2
#define O1 6
#define KK1 80
#define LP1 4058       // pooled length after conv1(pad=2,K=80) + avgpool2

#define O2 16
#define KK2 3
#define LP2 2028

#define NFLAT 32448    // 16*2028 = 507*64
#define H1 120
#define H2 84
#define NOUT 10

typedef _Float16 h2 __attribute__((ext_vector_type(2)));
typedef _Float16 f16x8 __attribute__((ext_vector_type(8)));
typedef float f32x4 __attribute__((ext_vector_type(4)));
#define BIGH ((_Float16)30000.0f)

__device__ __forceinline__ h2 bch2(float f) { return __builtin_bit_cast(h2, f); }
__device__ __forceinline__ unsigned bcu(float f) { return __builtin_bit_cast(unsigned, f); }
// odd-phase pair from adjacent even pairs: (cur.hi, nxt.lo) -> v_alignbit
__device__ __forceinline__ unsigned fsh(float nxt, float cur) {
  return (bcu(cur) >> 16) | (bcu(nxt) << 16);
}
// guaranteed-packed f16 ops (rule out compiler scalarization)
__device__ __forceinline__ unsigned pk_add(unsigned a, unsigned b) {
  unsigned d;
  asm("v_pk_add_f16 %0, %1, %2" : "=v"(d) : "v"(a), "v"(b));
  return d;
}
__device__ __forceinline__ unsigned pk_min(unsigned a, unsigned b) {
  unsigned d;
  asm("v_pk_min_f16 %0, %1, %2" : "=v"(d) : "v"(a), "v"(b));
  return d;
}

// ---------------- Kernel 0: pack w1 into half2 pairs (w[2m], w[2m+1]) ----------------
__global__ __launch_bounds__(256) void k_prep(const float* __restrict__ w1,
                                              float* __restrict__ whb) {
  const int idx = threadIdx.x + blockIdx.x * 256;
  if (idx >= (O1 * C1) * (KK1 / 2)) return;
  const int oc = idx / (KK1 / 2);
  const int m  = idx - oc * (KK1 / 2);
  h2 v;
  v.x = (_Float16)w1[oc * KK1 + 2 * m];
  v.y = (_Float16)w1[oc * KK1 + 2 * m + 1];
  whb[idx] = __builtin_bit_cast(float, v);
}

// ---------------- Kernel 1: tropical min-plus conv1 + avgpool2 ----------------
// v7: (1) inline-asm v_pk_add/min_f16 — guaranteed packed (six prior variants
// all ~41-47us; scalarized f16 vector ops are the prime suspect for VALU 2x);
// (2) 2 pooled j per thread — w LDS-broadcast reads amortized 2x
// (150 LDS instr / 2 outputs vs 120 / 1);
// (3) odd phase via v_alignbit, single packed A array.
// 512 blocks x 512 thr, launch_bounds(512,4) -> 2 blocks/CU, 16 waves/CU.
#define TJ1 512
#define NT1 8          // 8 tiles x 512 j = 4096 >= LP1
#define DWIN 555
#define DPAD 560

__global__ __launch_bounds__(512, 4) void k_conv1(const float* __restrict__ x,
                                                  const float* __restrict__ whb,
                                                  float* __restrict__ p1) {
  __shared__ float As[C1][DPAD];
  __shared__ unsigned ws[O1 * C1 * 40];     // 720 dwords (h2-pair packed)
  const int b    = blockIdx.x >> 3;
  const int tile = blockIdx.x & 7;
  const int j0   = tile * TJ1;
  const int tid  = threadIdx.x;             // 0..511

  for (int idx = tid; idx < O1 * C1 * 40; idx += 512)
    ws[idx] = ((const unsigned*)whb)[idx];
  for (int q = tid; q < C1 * DWIN; q += 512) {
    const int c = q / DWIN;
    const int d = q - c * DWIN;
    const int E = 2 * (j0 + d) - PAD1;
    const float* xc = x + ((size_t)b * C1 + c) * LIN;
    float f0 = 0.f, f1 = 0.f;
    if ((unsigned)E < LIN) f0 = xc[E];
    if ((unsigned)(E + 1) < LIN) f1 = xc[E + 1];
    h2 A; A.x = (_Float16)f0; A.y = (_Float16)f1;
    As[c][d] = __builtin_bit_cast(float, A);
  }
  __syncthreads();

  const int og = tid >> 8;               // 0/1 (wave-uniform)
  const int jj = tid & 255;
  const int ob = og * 3;                 // o in {ob, ob+1, ob+2}

  h2 binit; binit.x = BIGH; binit.y = BIGH;
  const unsigned BIG2 = __builtin_bit_cast(unsigned, binit);

  float r[2][3] = {{0.f, 0.f, 0.f}, {0.f, 0.f, 0.f}};

  for (int c = 0; c < C1; ++c) {
    unsigned aA[2][3], aB[2][3];
#pragma unroll
    for (int t = 0; t < 2; ++t)
#pragma unroll
      for (int oo = 0; oo < 3; ++oo) { aA[t][oo] = BIG2; aB[t][oo] = BIG2; }

    float4 cur0 = *(const float4*)&As[c][jj];
    float4 cur1 = *(const float4*)&As[c][jj + 256];
#pragma unroll
    for (int mq = 0; mq < 10; ++mq) {
      float4 nxt0 = *(const float4*)&As[c][jj + 4 * mq + 4];
      float4 nxt1 = *(const float4*)&As[c][jj + 256 + 4 * mq + 4];
      unsigned A0[4] = {bcu(cur0.x), bcu(cur0.y), bcu(cur0.z), bcu(cur0.w)};
      unsigned A1[4] = {bcu(cur1.x), bcu(cur1.y), bcu(cur1.z), bcu(cur1.w)};
      unsigned B0[4] = {fsh(cur0.y, cur0.x), fsh(cur0.z, cur0.y),
                        fsh(cur0.w, cur0.z), fsh(nxt0.x, cur0.w)};
      unsigned B1[4] = {fsh(cur1.y, cur1.x), fsh(cur1.z, cur1.y),
                        fsh(cur1.w, cur1.z), fsh(nxt1.x, cur1.w)};
#pragma unroll
      for (int oo = 0; oo < 3; ++oo) {
        uint4 wq = *(const uint4*)&ws[((ob + oo) * C1 + c) * 40 + 4 * mq]; // uniform
        unsigned wv[4] = {wq.x, wq.y, wq.z, wq.w};
#pragma unroll
        for (int t = 0; t < 4; ++t) {
          aA[0][oo] = pk_min(aA[0][oo], pk_add(A0[t], wv[t]));
          aB[0][oo] = pk_min(aB[0][oo], pk_add(B0[t], wv[t]));
          aA[1][oo] = pk_min(aA[1][oo], pk_add(A1[t], wv[t]));
          aB[1][oo] = pk_min(aB[1][oo], pk_add(B1[t], wv[t]));
        }
      }
      cur0 = nxt0; cur1 = nxt1;
    }
#pragma unroll
    for (int t = 0; t < 2; ++t)
#pragma unroll
      for (int oo = 0; oo < 3; ++oo) {
        h2 va = __builtin_bit_cast(h2, aA[t][oo]);
        h2 vb = __builtin_bit_cast(h2, aB[t][oo]);
        r[t][oo] += fminf((float)va.x, (float)va.y) + fminf((float)vb.x, (float)vb.y);
      }
  }

#pragma unroll
  for (int t = 0; t < 2; ++t) {
    const int j = j0 + t * 256 + jj;
    if (j < LP1) {
      float* pb = p1 + (size_t)b * O1 * LP1 + j;
      pb[(ob + 0) * LP1] = 0.5f * r[t][0];
      pb[(ob + 1) * LP1] = 0.5f * r[t][1];
      pb[(ob + 2) * LP1] = 0.5f * r[t][2];
    }
  }
}

// ---------------- Kernel 2: tropical max-plus conv2 (K=3) + avgpool2 -> f16 ----------------
#define T2 256
#define XT2 516

__global__ __launch_bounds__(256) void k_conv2(const float* __restrict__ p1,
                                               const float* __restrict__ w2,
                                               _Float16* __restrict__ p2h) {
  __shared__ float ps[O1][XT2];
  __shared__ float w2s[O2 * O1 * KK2];   // 288 floats
  const int b    = blockIdx.x >> 3;
  const int tile = blockIdx.x & 7;
  const int j0   = tile * T2;
  const int tid  = threadIdx.x;

  for (int idx = tid; idx < O2 * O1 * KK2; idx += 256) w2s[idx] = w2[idx];
  for (int idx = tid; idx < O1 * XT2; idx += 256) {
    int c = idx / XT2;
    int p = idx - c * XT2;
    int t = 2 * j0 + p;
    ps[c][p] = (t < LP1) ? p1[((size_t)b * O1 + c) * LP1 + t] : 0.f;
  }
  __syncthreads();

  const int j = j0 + tid;
  if (j >= LP2) return;
  const int lb = 2 * tid;
  float xv[O1][4];
#pragma unroll
  for (int c = 0; c < O1; ++c) {
    xv[c][0] = ps[c][lb];     xv[c][1] = ps[c][lb + 1];
    xv[c][2] = ps[c][lb + 2]; xv[c][3] = ps[c][lb + 3];
  }
#pragma unroll
  for (int o = 0; o < O2; ++o) {
    float s = 0.f;
#pragma unroll
    for (int c = 0; c < O1; ++c) {
      float w0  = w2s[(o * O1 + c) * KK2 + 0];
      float w1v = w2s[(o * O1 + c) * KK2 + 1];
      float w2v = w2s[(o * O1 + c) * KK2 + 2];
      float m0 = fmaxf(fmaxf(xv[c][0] + w0, xv[c][1] + w1v), xv[c][2] + w2v);
      float m1 = fmaxf(fmaxf(xv[c][1] + w0, xv[c][2] + w1v), xv[c][3] + w2v);
      s += m0 + m1;
    }
    p2h[(size_t)b * NFLAT + o * LP2 + j] = (_Float16)(0.5f * s);
  }
}

// ---------------- Kernel 3: FC1 split-K via MFMA f16 ----------------
#define KC2 64
#define NKC2 507

__global__ __launch_bounds__(256) void k_fc1(const _Float16* __restrict__ p2h,
                                             const float* __restrict__ w,
                                             _Float16* __restrict__ part) {
  __shared__ _Float16 bs[64][KC2];    // [b][k], 8 KB
  const int kc  = blockIdx.x;
  const int k0  = kc * KC2;
  const int tid = threadIdx.x;

#pragma unroll
  for (int r = 0; r < 2; ++r) {
    const int task = tid + 256 * r;        // 0..511
    const int row  = task >> 3;
    const int c4   = task & 7;
    float4 v = *(const float4*)&p2h[(size_t)row * NFLAT + k0 + c4 * 8];
    *(float4*)&bs[row][c4 * 8] = v;
  }
  __syncthreads();

  const int lane = tid & 63;
  const int wid  = tid >> 6;             // 0..3
  const int m_l  = lane & 15;
  const int q    = lane >> 4;            // 0..3
  const int m0   = wid * 32;

  const int rowA0 = m0 + m_l;            // <= 111, always valid
  int rowA1 = m0 + 16 + m_l;             // <= 127; clamp pad rows
  if (rowA1 > H1 - 1) rowA1 = H1 - 1;
  const float* wp0 = w + (size_t)rowA0 * NFLAT + k0 + q * 8;
  const float* wp1 = w + (size_t)rowA1 * NFLAT + k0 + q * 8;

  f32x4 acc[2][4];
#pragma unroll
  for (int t = 0; t < 2; ++t)
#pragma unroll
    for (int nt = 0; nt < 4; ++nt) acc[t][nt] = (f32x4){0.f, 0.f, 0.f, 0.f};

#pragma unroll
  for (int ks = 0; ks < 2; ++ks) {
    float4 a0l = *(const float4*)(wp0 + ks * 32);
    float4 a0h = *(const float4*)(wp0 + ks * 32 + 4);
    float4 a1l = *(const float4*)(wp1 + ks * 32);
    float4 a1h = *(const float4*)(wp1 + ks * 32 + 4);
    f16x8 A0, A1;
    A0[0] = (_Float16)a0l.x; A0[1] = (_Float16)a0l.y;
    A0[2] = (_Float16)a0l.z; A0[3] = (_Float16)a0l.w;
    A0[4] = (_Float16)a0h.x; A0[5] = (_Float16)a0h.y;
    A0[6] = (_Float16)a0h.z; A0[7] = (_Float16)a0h.w;
    A1[0] = (_Float16)a1l.x; A1[1] = (_Float16)a1l.y;
    A1[2] = (_Float16)a1l.z; A1[3] = (_Float16)a1l.w;
    A1[4] = (_Float16)a1h.x; A1[5] = (_Float16)a1h.y;
    A1[6] = (_Float16)a1h.z; A1[7] = (_Float16)a1h.w;
#pragma unroll
    for (int nt = 0; nt < 4; ++nt) {
      f16x8 Bf = *(const f16x8*)&bs[nt * 16 + m_l][ks * 32 + q * 8];
      acc[0][nt] = __builtin_amdgcn_mfma_f32_16x16x32_f16(A0, Bf, acc[0][nt], 0, 0, 0);
      acc[1][nt] = __builtin_amdgcn_mfma_f32_16x16x32_f16(A1, Bf, acc[1][nt], 0, 0, 0);
    }
  }

#pragma unroll
  for (int t = 0; t < 2; ++t)
#pragma unroll
    for (int nt = 0; nt < 4; ++nt)
#pragma unroll
      for (int r = 0; r < 4; ++r) {
        const int i = m0 + t * 16 + q * 4 + r;
        if (i < H1)
          part[((size_t)kc * H1 + i) * 64 + nt * 16 + m_l] = (_Float16)acc[t][nt][r];
      }
}

// ---------------- Kernel 3b: reduce partials -> part2[4][120][64] f32 ----------------
__global__ __launch_bounds__(512) void k_fc1red(const _Float16* __restrict__ part,
                                                float* __restrict__ part2) {
  __shared__ float red[512];
  const int bx  = blockIdx.x;            // 0..479
  const int s   = bx / H1;               // 0..3
  const int i   = bx - s * H1;           // 0..119
  const int tid = threadIdx.x;
  const int b   = tid & 63;
  const int sub = tid >> 6;              // 0..7
  const int kc0 = s * 127;
  const int kc1 = (kc0 + 127 < NKC2) ? kc0 + 127 : NKC2;
  float acc = 0.f;
  for (int kc = kc0 + sub; kc < kc1; kc += 8)
    acc += (float)part[((size_t)kc * H1 + i) * 64 + b];
  red[tid] = acc;
  __syncthreads();
  if (tid < 64) {
    float t = 0.f;
#pragma unroll
    for (int s2 = 0; s2 < 8; ++s2) t += red[b + 64 * s2];
    part2[((size_t)s * H1 + i) * 64 + b] = t;
  }
}

// ---------------- Kernel 4: bias+ReLU, FC2+ReLU, FC3 ----------------
__global__ __launch_bounds__(128) void k_head(const float* __restrict__ part2,
                                              const float* __restrict__ fc1_b,
                                              const float* __restrict__ fc2_w,
                                              const float* __restrict__ fc2_b,
                                              const float* __restrict__ fc3_w,
                                              const float* __restrict__ fc3_b,
                                              float* __restrict__ out) {
  __shared__ float h1s[H1];
  __shared__ float h2s[H2];
  const int b = blockIdx.x;
  const int tid = threadIdx.x;
  if (tid < H1) {
    float v = part2[((size_t)0 * H1 + tid) * 64 + b]
            + part2[((size_t)1 * H1 + tid) * 64 + b]
            + part2[((size_t)2 * H1 + tid) * 64 + b]
            + part2[((size_t)3 * H1 + tid) * 64 + b];
    h1s[tid] = fmaxf(v + fc1_b[tid], 0.f);
  }
  __syncthreads();
  if (tid < H2) {
    float s = fc2_b[tid];
#pragma unroll 4
    for (int n = 0; n < H1; ++n) s += h1s[n] * fc2_w[tid * H1 + n];
    h2s[tid] = fmaxf(s, 0.f);
  }
  __syncthreads();
  if (tid < NOUT) {
    float s = fc3_b[tid];
#pragma unroll 4
    for (int n = 0; n < H2; ++n) s += h2s[n] * fc3_w[tid * H2 + n];
    out[b * NOUT + tid] = s;
  }
}

extern "C" void kernel_launch(void* const* d_in, const int* in_sizes, int n_in,
                              void* d_out, int out_size, void* d_ws, size_t ws_size,
                              hipStream_t stream) {
  const float* x     = (const float*)d_in[0];
  const float* w1    = (const float*)d_in[1];
  const float* w2    = (const float*)d_in[2];
  const float* fc1_w = (const float*)d_in[3];
  const float* fc1_b = (const float*)d_in[4];
  const float* fc2_w = (const float*)d_in[5];
  const float* fc2_b = (const float*)d_in[6];
  const float* fc3_w = (const float*)d_in[7];
  const float* fc3_b = (const float*)d_in[8];

  float* ws = (float*)d_ws;
  float*     p1    = ws;                                        // 1,558,272 f
  _Float16*  p2h   = (_Float16*)(p1 + (size_t)BB * O1 * LP1);   // 2,076,672 h
  _Float16*  part  = p2h + (size_t)BB * NFLAT;                  // 507*120*64 h
  float*     part2 = (float*)(part + (size_t)NKC2 * H1 * 64);   // 4*120*64 f
  float*     whb   = part2 + (size_t)4 * H1 * 64;               // 720 f
  float*     out   = (float*)d_out;

  hipLaunchKernelGGL(k_prep, dim3(3), dim3(256), 0, stream, w1, whb);
  hipLaunchKernelGGL(k_conv1, dim3(BB * NT1), dim3(512), 0, stream, x, whb, p1);
  hipLaunchKernelGGL(k_conv2, dim3(BB * 8), dim3(256), 0, stream, p1, w2, p2h);
  hipLaunchKernelGGL(k_fc1, dim3(NKC2), dim3(256), 0, stream, p2h, fc1_w, part);
  hipLaunchKernelGGL(k_fc1red, dim3(4 * H1), dim3(512), 0, stream, part, part2);
  hipLaunchKernelGGL(k_head, dim3(BB), dim3(128), 0, stream, part2, fc1_b, fc2_w, fc2_b,
                     fc3_w, fc3_b, out);
}